// Round 15
// baseline (442.444 us; speedup 1.0000x reference)
//
#include <hip/hip_runtime.h>
#include <hip/hip_bf16.h>

#define TT 1024
#define KS 64

typedef __attribute__((ext_vector_type(8))) short bf16x8;
typedef __attribute__((ext_vector_type(4))) float f32x4;

__device__ __forceinline__ unsigned short f2bf(float x) {
    union { __hip_bfloat16 h; unsigned short s; } u;
    u.h = __float2bfloat16(x);
    return u.s;
}
__device__ __forceinline__ float bflo(unsigned u) {
    union { unsigned v; float f; } w; w.v = u << 16; return w.f;
}
__device__ __forceinline__ float bfhi(unsigned u) {
    union { unsigned v; float f; } w; w.v = u & 0xFFFF0000u; return w.f;
}
__device__ __forceinline__ unsigned cvtpk(float a, float b) {
    unsigned r;
    asm("v_cvt_pk_bf16_f32 %0, %1, %2" : "=v"(r) : "v"(a), "v"(b));
    return r;
}
__device__ __forceinline__ unsigned pkadd(unsigned a, unsigned b) {
    unsigned r;
    asm("v_pk_add_u16 %0, %1, %2" : "=v"(r) : "v"(a), "v"(b));
    return r;
}

// ---------------------------------------------------------------------------
// Pre-pass: g = bf16 exp(emissions) (r11-proven), memory-bound streaming.
// ---------------------------------------------------------------------------
__global__ __launch_bounds__(256) void crf_expem_bf16(
    const float* __restrict__ em, uint4* __restrict__ g, long long n8)
{
    long long i = (long long)blockIdx.x * blockDim.x + threadIdx.x;
    const long long stride = (long long)gridDim.x * blockDim.x;
    const float4* p = (const float4*)em;
    for (; i < n8; i += stride) {
        float4 a = p[i * 2], b = p[i * 2 + 1];
        uint4 o;
        o.x = (unsigned)f2bf(__expf(a.x)) | ((unsigned)f2bf(__expf(a.y)) << 16);
        o.y = (unsigned)f2bf(__expf(a.z)) | ((unsigned)f2bf(__expf(a.w)) << 16);
        o.z = (unsigned)f2bf(__expf(b.x)) | ((unsigned)f2bf(__expf(b.y)) << 16);
        o.w = (unsigned)f2bf(__expf(b.z)) | ((unsigned)f2bf(__expf(b.w)) << 16);
        g[i] = o;
    }
}

// ---------------------------------------------------------------------------
// Fused kernel. Blocks [0,nZ): logZ, TWO interleaved 16-seq chains per wave
// (chain A = batches blk*32..+15, chain B = +16..+31). Chains are fully
// independent; issue order per t is [MFMA A][MFMA B][tail A][tail B] so each
// chain's dependency stalls hide under the other's work. E fragments are
// SHARED between chains (same transitions). Blocks [nZ,nZ+B): gold score.
//
// Verified pieces carried over unchanged: sigma lane-local repack
// (r7/r8/r11/r13), bf16-g unpack tail (r11), asm-volatile flat loads
// (anti-sink, r7) with straight-line control flow while in flight (r9),
// counted vmcnt + sched_barrier (rule #18), clamped refills + dummy masked
// step t=1024 (r8), deadbeat measure-once/apply-once controller (r10),
// M += sln2 exact bookkeeping.
// Ledger: 3 loads/slot, 2 slots/chain, 2 chains = 12 in flight; each
// sub-step waits vmcnt(9) (oldest slot's 3 done), consumes, reissues 3.
// ---------------------------------------------------------------------------
__global__ __launch_bounds__(256, 1) void crf_fused2(
    const float* __restrict__ em,
    const uint4* __restrict__ g4,       // bf16 exp(em)
    const int* __restrict__ mask,
    const int* __restrict__ tags,
    const float* __restrict__ trans,
    const float* __restrict__ startT,
    const float* __restrict__ endT,
    float* __restrict__ logZ,
    float* __restrict__ gold,
    int nZ)
{
    __shared__ float wacc[4];
    __shared__ int   wcnt[4];

    if ((int)blockIdx.x >= nZ) {
        // ---------------- gold path score (one block per batch) ------------
        const int b = (int)blockIdx.x - nZ;
        const int tid = threadIdx.x;
        const float* emb = em + (size_t)b * TT * KS;
        const int* tb = tags + (size_t)b * TT;
        const int* mb = mask + (size_t)b * TT;

        float acc = 0.f;
        int cnt = 0;
        for (int t = tid; t < TT; t += 256) {
            int tg = tb[t];
            int mv = mb[t];
            float mf = mv ? 1.f : 0.f;
            acc += emb[t * KS + tg] * mf;
            if (t >= 1) acc += trans[tb[t - 1] * KS + tg] * mf;
            cnt += mv ? 1 : 0;
        }
#pragma unroll
        for (int off = 32; off; off >>= 1) {
            acc += __shfl_xor(acc, off);
            cnt += __shfl_xor(cnt, off);
        }
        int wv = tid >> 6;
        if ((tid & 63) == 0) { wacc[wv] = acc; wcnt[wv] = cnt; }
        __syncthreads();
        if (tid == 0) {
            float a = wacc[0] + wacc[1] + wacc[2] + wacc[3];
            int   cc = wcnt[0] + wcnt[1] + wcnt[2] + wcnt[3];
            gold[b] = a + startT[tb[0]] + endT[tb[cc - 1]];
        }
        return;
    }

    // ---------------- logZ, two interleaved chains (wave 0 only) -----------
    if (threadIdx.x >= 64) return;
    __builtin_amdgcn_s_setprio(1);

    const int l = threadIdx.x;
    const int c = l & 15;
    const int h = l >> 4;
    const long long bA = (long long)blockIdx.x * 32 + c;
    const long long bB = bA + 16;

    // constant transition fragments (A-operand), shared by both chains
    const int sigc = 8 * (c >> 2) + (c & 3);
    bf16x8 E[4][2];
#pragma unroll
    for (int m = 0; m < 4; ++m) {
        const int col = 32 * (m >> 1) + 4 * (m & 1) + sigc;
#pragma unroll
        for (int kk = 0; kk < 2; ++kk) {
            union { unsigned short s[8]; bf16x8 v; } u;
#pragma unroll
            for (int e = 0; e < 8; ++e)
                u.s[e] = f2bf(__expf(trans[(32 * kk + 8 * h + e) * KS + col]));
            E[m][kk] = u.v;
        }
    }

    const long long embA = bA * (long long)TT * KS;
    const long long embB = bB * (long long)TT * KS;
    const unsigned long long gpA =
        (unsigned long long)(const void*)((const char*)g4 + embA * 2 + h * 16);
    const unsigned long long gpB =
        (unsigned long long)(const void*)((const char*)g4 + embB * 2 + h * 16);
    const unsigned long long mpA =
        (unsigned long long)(const void*)(mask + bA * TT);
    const unsigned long long mpB =
        (unsigned long long)(const void*)(mask + bB * TT);

    // ---- state init at t=0 for both chains ----
    unsigned awA0, awA1, awA2, awA3, awA4, awA5, awA6, awA7;
    unsigned awB0, awB1, awB2, awB3, awB4, awB5, awB6, awB7;
    {
        const float* erA = em + embA;
        const float* erB = em + embB;
        float wa[16], wb[16];
#pragma unroll
        for (int kk = 0; kk < 2; ++kk)
#pragma unroll
            for (int e = 0; e < 8; ++e) {
                const int j = 32 * kk + 8 * h + e;
                wa[8 * kk + e] = __expf(erA[j] + startT[j]);
                wb[8 * kk + e] = __expf(erB[j] + startT[j]);
            }
        awA0 = cvtpk(wa[0], wa[1]);   awA1 = cvtpk(wa[2], wa[3]);
        awA2 = cvtpk(wa[4], wa[5]);   awA3 = cvtpk(wa[6], wa[7]);
        awA4 = cvtpk(wa[8], wa[9]);   awA5 = cvtpk(wa[10], wa[11]);
        awA6 = cvtpk(wa[12], wa[13]); awA7 = cvtpk(wa[14], wa[15]);
        awB0 = cvtpk(wb[0], wb[1]);   awB1 = cvtpk(wb[2], wb[3]);
        awB2 = cvtpk(wb[4], wb[5]);   awB3 = cvtpk(wb[6], wb[7]);
        awB4 = cvtpk(wb[8], wb[9]);   awB5 = cvtpk(wb[10], wb[11]);
        awB6 = cvtpk(wb[12], wb[13]); awB7 = cvtpk(wb[14], wb[15]);
    }
    float MA = 0.f, MB = 0.f;

    // ---- prefetch slots: depth 2 per chain, 3 loads per slot ----
    uint4 gaA[2], gcA[2], gaB[2], gcB[2];
    int   mvA[2], mvB[2];
#pragma unroll
    for (int u = 0; u < 2; ++u) {
        const unsigned long long aa = gpA + (unsigned long long)(1 + u) * 128ull;
        const unsigned long long ab = gpB + (unsigned long long)(1 + u) * 128ull;
        const unsigned long long ma = mpA + (unsigned long long)(1 + u) * 4ull;
        const unsigned long long mb = mpB + (unsigned long long)(1 + u) * 4ull;
        asm volatile("global_load_dwordx4 %0, %1, off" : "=&v"(gaA[u]) : "v"(aa));
        asm volatile("global_load_dwordx4 %0, %1, off offset:64" : "=&v"(gcA[u]) : "v"(aa));
        asm volatile("global_load_dword %0, %1, off" : "=&v"(mvA[u]) : "v"(ma));
        asm volatile("global_load_dwordx4 %0, %1, off" : "=&v"(gaB[u]) : "v"(ab));
        asm volatile("global_load_dwordx4 %0, %1, off offset:64" : "=&v"(gcB[u]) : "v"(ab));
        asm volatile("global_load_dword %0, %1, off" : "=&v"(mvB[u]) : "v"(mb));
    }

    unsigned kaddA = 0, kaddB = 0;
    float sln2A = 0.f, sln2B = 0.f;

#define CRF_CTRL(W0, W4, KADD, SLN2) do {                                      \
    const unsigned l0 = (W0) & 0xffffu, h0 = (W0) >> 16;                       \
    const unsigned l4 = (W4) & 0xffffu, h4 = (W4) >> 16;                       \
    unsigned um = l0 > h0 ? l0 : h0;                                           \
    um = um > l4 ? um : l4;  um = um > h4 ? um : h4;                           \
    unsigned sx = (unsigned)__shfl_xor((int)um, 16); um = um > sx ? um : sx;   \
    sx = (unsigned)__shfl_xor((int)um, 32);          um = um > sx ? um : sx;   \
    const unsigned k16 = (0x3F80u - (um & 0x7F80u)) & 0xffffu;                 \
    KADD = (k16 << 16) | k16;                                                  \
    SLN2 = (float)((int)((um >> 7) & 0xffu) - 127) * 0.693147180559945f;       \
} while (0)

// one chain's tail+refill (used inside the double-step)
#define CRF_TAIL(SFX, t, u, APPLY, DOCTRL, GP, MP, d0, d1, d2, d3)             \
do {                                                                           \
    const uint4 v0 = ga##SFX[u], v1 = gc##SFX[u];                              \
    const int mvv = ((t) <= TT - 1) ? mv##SFX[u] : 0;                          \
    {                                                                          \
        const int tn = ((t) + 2 <= TT - 1) ? ((t) + 2) : (TT - 1);             \
        const unsigned long long a  = (GP) + (unsigned long long)tn * 128ull;  \
        const unsigned long long ma = (MP) + (unsigned long long)tn * 4ull;    \
        asm volatile("global_load_dwordx4 %0, %1, off" : "=&v"(ga##SFX[u]) : "v"(a)); \
        asm volatile("global_load_dwordx4 %0, %1, off offset:64" : "=&v"(gc##SFX[u]) : "v"(a)); \
        asm volatile("global_load_dword %0, %1, off" : "=&v"(mv##SFX[u]) : "v"(ma)); \
    }                                                                          \
    const float g00 = bflo(v0.x), g01 = bfhi(v0.x);                            \
    const float g02 = bflo(v0.y), g03 = bfhi(v0.y);                            \
    const float g10 = bflo(v0.z), g11 = bfhi(v0.z);                            \
    const float g12 = bflo(v0.w), g13 = bfhi(v0.w);                            \
    const float g20 = bflo(v1.x), g21 = bfhi(v1.x);                            \
    const float g22 = bflo(v1.y), g23 = bfhi(v1.y);                            \
    const float g30 = bflo(v1.z), g31 = bfhi(v1.z);                            \
    const float g32 = bflo(v1.w), g33 = bfhi(v1.w);                            \
    unsigned q0, q1, q2, q3, q4, q5, q6, q7;                                   \
    if (APPLY) {                                                               \
        q0 = pkadd(cvtpk(d0.x * g00, d0.y * g01), kadd##SFX);                  \
        q1 = pkadd(cvtpk(d0.z * g02, d0.w * g03), kadd##SFX);                  \
        q2 = pkadd(cvtpk(d1.x * g10, d1.y * g11), kadd##SFX);                  \
        q3 = pkadd(cvtpk(d1.z * g12, d1.w * g13), kadd##SFX);                  \
        q4 = pkadd(cvtpk(d2.x * g20, d2.y * g21), kadd##SFX);                  \
        q5 = pkadd(cvtpk(d2.z * g22, d2.w * g23), kadd##SFX);                  \
        q6 = pkadd(cvtpk(d3.x * g30, d3.y * g31), kadd##SFX);                  \
        q7 = pkadd(cvtpk(d3.z * g32, d3.w * g33), kadd##SFX);                  \
    } else {                                                                   \
        q0 = cvtpk(d0.x * g00, d0.y * g01);                                    \
        q1 = cvtpk(d0.z * g02, d0.w * g03);                                    \
        q2 = cvtpk(d1.x * g10, d1.y * g11);                                    \
        q3 = cvtpk(d1.z * g12, d1.w * g13);                                    \
        q4 = cvtpk(d2.x * g20, d2.y * g21);                                    \
        q5 = cvtpk(d2.z * g22, d2.w * g23);                                    \
        q6 = cvtpk(d3.x * g30, d3.y * g31);                                    \
        q7 = cvtpk(d3.z * g32, d3.w * g33);                                    \
    }                                                                          \
    aw##SFX##0 = mvv ? q0 : aw##SFX##0; aw##SFX##1 = mvv ? q1 : aw##SFX##1;    \
    aw##SFX##2 = mvv ? q2 : aw##SFX##2; aw##SFX##3 = mvv ? q3 : aw##SFX##3;    \
    aw##SFX##4 = mvv ? q4 : aw##SFX##4; aw##SFX##5 = mvv ? q5 : aw##SFX##5;    \
    aw##SFX##6 = mvv ? q6 : aw##SFX##6; aw##SFX##7 = mvv ? q7 : aw##SFX##7;    \
    if (APPLY) { M##SFX = mvv ? (M##SFX + sln2##SFX) : M##SFX; }               \
    if (DOCTRL) CRF_CTRL(aw##SFX##0, aw##SFX##4, kadd##SFX, sln2##SFX);        \
} while (0)

#define CRF_DSTEP(t, u, APPLY, DOCTRL) do {                                    \
    union { unsigned uu[4]; bf16x8 v; } Aa0, Aa1, Ba0, Ba1;                    \
    Aa0.uu[0] = awA0; Aa0.uu[1] = awA1; Aa0.uu[2] = awA2; Aa0.uu[3] = awA3;    \
    Aa1.uu[0] = awA4; Aa1.uu[1] = awA5; Aa1.uu[2] = awA6; Aa1.uu[3] = awA7;    \
    Ba0.uu[0] = awB0; Ba0.uu[1] = awB1; Ba0.uu[2] = awB2; Ba0.uu[3] = awB3;    \
    Ba1.uu[0] = awB4; Ba1.uu[1] = awB5; Ba1.uu[2] = awB6; Ba1.uu[3] = awB7;    \
    const f32x4 z = {0.f, 0.f, 0.f, 0.f};                                      \
    f32x4 dA0 = __builtin_amdgcn_mfma_f32_16x16x32_bf16(E[0][0], Aa0.v, z,0,0,0); \
    f32x4 dA1 = __builtin_amdgcn_mfma_f32_16x16x32_bf16(E[1][0], Aa0.v, z,0,0,0); \
    f32x4 dA2 = __builtin_amdgcn_mfma_f32_16x16x32_bf16(E[2][0], Aa0.v, z,0,0,0); \
    f32x4 dA3 = __builtin_amdgcn_mfma_f32_16x16x32_bf16(E[3][0], Aa0.v, z,0,0,0); \
    dA0 = __builtin_amdgcn_mfma_f32_16x16x32_bf16(E[0][1], Aa1.v, dA0, 0,0,0); \
    dA1 = __builtin_amdgcn_mfma_f32_16x16x32_bf16(E[1][1], Aa1.v, dA1, 0,0,0); \
    dA2 = __builtin_amdgcn_mfma_f32_16x16x32_bf16(E[2][1], Aa1.v, dA2, 0,0,0); \
    dA3 = __builtin_amdgcn_mfma_f32_16x16x32_bf16(E[3][1], Aa1.v, dA3, 0,0,0); \
    f32x4 dB0 = __builtin_amdgcn_mfma_f32_16x16x32_bf16(E[0][0], Ba0.v, z,0,0,0); \
    f32x4 dB1 = __builtin_amdgcn_mfma_f32_16x16x32_bf16(E[1][0], Ba0.v, z,0,0,0); \
    f32x4 dB2 = __builtin_amdgcn_mfma_f32_16x16x32_bf16(E[2][0], Ba0.v, z,0,0,0); \
    f32x4 dB3 = __builtin_amdgcn_mfma_f32_16x16x32_bf16(E[3][0], Ba0.v, z,0,0,0); \
    dB0 = __builtin_amdgcn_mfma_f32_16x16x32_bf16(E[0][1], Ba1.v, dB0, 0,0,0); \
    dB1 = __builtin_amdgcn_mfma_f32_16x16x32_bf16(E[1][1], Ba1.v, dB1, 0,0,0); \
    dB2 = __builtin_amdgcn_mfma_f32_16x16x32_bf16(E[2][1], Ba1.v, dB2, 0,0,0); \
    dB3 = __builtin_amdgcn_mfma_f32_16x16x32_bf16(E[3][1], Ba1.v, dB3, 0,0,0); \
    asm volatile("s_waitcnt vmcnt(9)" ::: "memory");                           \
    __builtin_amdgcn_sched_barrier(0);                                         \
    CRF_TAIL(A, t, u, APPLY, DOCTRL, gpA, mpA, dA0, dA1, dA2, dA3);            \
    asm volatile("s_waitcnt vmcnt(9)" ::: "memory");                           \
    __builtin_amdgcn_sched_barrier(0);                                         \
    CRF_TAIL(B, t, u, APPLY, DOCTRL, gpB, mpB, dB0, dB1, dB2, dB3);            \
} while (0)

    // groups of 4 t-steps; slots u = 0,1,0,1; measure @ds0, apply once @ds2
    for (int t0 = 1; t0 < TT + 1; t0 += 4) {
        CRF_DSTEP(t0 + 0, 0, 0, 1);
        CRF_DSTEP(t0 + 1, 1, 0, 0);
        CRF_DSTEP(t0 + 2, 0, 1, 0);
        CRF_DSTEP(t0 + 3, 1, 0, 0);
    }
#undef CRF_DSTEP
#undef CRF_TAIL
#undef CRF_CTRL
    __builtin_amdgcn_s_setprio(0);

    // logZ = M + log(sum_j w_j * exp(end_j)) for both chains
    float endE[16];
#pragma unroll
    for (int kk = 0; kk < 2; ++kk)
#pragma unroll
        for (int wi = 0; wi < 4; ++wi) {
            const int j0 = 32 * kk + 8 * h + 2 * wi;
            endE[8 * kk + 2 * wi] = __expf(endT[j0]);
            endE[8 * kk + 2 * wi + 1] = __expf(endT[j0 + 1]);
        }
    float valA = 0.f, valB = 0.f;
    {
        const unsigned aA[8] = {awA0, awA1, awA2, awA3, awA4, awA5, awA6, awA7};
        const unsigned aB[8] = {awB0, awB1, awB2, awB3, awB4, awB5, awB6, awB7};
#pragma unroll
        for (int kk = 0; kk < 2; ++kk)
#pragma unroll
            for (int wi = 0; wi < 4; ++wi) {
                const unsigned wqA = aA[4 * kk + wi];
                const unsigned wqB = aB[4 * kk + wi];
                valA += bflo(wqA) * endE[8 * kk + 2 * wi];
                valA += bfhi(wqA) * endE[8 * kk + 2 * wi + 1];
                valB += bflo(wqB) * endE[8 * kk + 2 * wi];
                valB += bfhi(wqB) * endE[8 * kk + 2 * wi + 1];
            }
    }
    valA += __shfl_xor(valA, 16);
    valA += __shfl_xor(valA, 32);
    valB += __shfl_xor(valB, 16);
    valB += __shfl_xor(valB, 32);
    if (l < 16) {
        logZ[(long long)blockIdx.x * 32 + l]      = MA + __logf(valA);
        logZ[(long long)blockIdx.x * 32 + 16 + l] = MB + __logf(valB);
    }
}

// ---------------------------------------------------------------------------
// Fallback (workspace too small): r7-verified kernel, exp on the fly.
// ---------------------------------------------------------------------------
__global__ __launch_bounds__(64, 1) void crf_logZ_fb(
    const float* __restrict__ em, const int* __restrict__ mask,
    const float* __restrict__ trans, const float* __restrict__ startT,
    const float* __restrict__ endT, float* __restrict__ logZ)
{
    const int l = threadIdx.x;
    const int c = l & 15;
    const int h = l >> 4;
    const long long b = (long long)blockIdx.x * 16 + c;

    const int sigc = 8 * (c >> 2) + (c & 3);
    bf16x8 E[4][2];
#pragma unroll
    for (int m = 0; m < 4; ++m) {
        const int col = 32 * (m >> 1) + 4 * (m & 1) + sigc;
#pragma unroll
        for (int kk = 0; kk < 2; ++kk) {
            union { unsigned short s[8]; bf16x8 v; } u;
#pragma unroll
            for (int e = 0; e < 8; ++e)
                u.s[e] = f2bf(__expf(trans[(32 * kk + 8 * h + e) * KS + col]));
            E[m][kk] = u.v;
        }
    }
    const long long embase = b * (long long)TT * KS;
    const int* mrow = mask + b * TT;
    const float* erow = em + embase;

    unsigned aw[8];
    {
        float w0[16];
#pragma unroll
        for (int kk = 0; kk < 2; ++kk)
#pragma unroll
            for (int e = 0; e < 8; ++e) {
                const int j = 32 * kk + 8 * h + e;
                w0[8 * kk + e] = __expf(erow[j] + startT[j]);
            }
#pragma unroll
        for (int i = 0; i < 8; ++i) aw[i] = cvtpk(w0[2 * i], w0[2 * i + 1]);
    }
    float M = 0.f;

    for (int t = 1; t < TT; ++t) {
        union { unsigned uu[4]; bf16x8 v; } A0, A1;
#pragma unroll
        for (int i = 0; i < 4; ++i) { A0.uu[i] = aw[i]; A1.uu[i] = aw[4 + i]; }
        const f32x4 z = {0.f, 0.f, 0.f, 0.f};
        f32x4 d0 = __builtin_amdgcn_mfma_f32_16x16x32_bf16(E[0][0], A0.v, z,0,0,0);
        f32x4 d1 = __builtin_amdgcn_mfma_f32_16x16x32_bf16(E[1][0], A0.v, z,0,0,0);
        f32x4 d2 = __builtin_amdgcn_mfma_f32_16x16x32_bf16(E[2][0], A0.v, z,0,0,0);
        f32x4 d3 = __builtin_amdgcn_mfma_f32_16x16x32_bf16(E[3][0], A0.v, z,0,0,0);
        d0 = __builtin_amdgcn_mfma_f32_16x16x32_bf16(E[0][1], A1.v, d0, 0,0,0);
        d1 = __builtin_amdgcn_mfma_f32_16x16x32_bf16(E[1][1], A1.v, d1, 0,0,0);
        d2 = __builtin_amdgcn_mfma_f32_16x16x32_bf16(E[2][1], A1.v, d2, 0,0,0);
        d3 = __builtin_amdgcn_mfma_f32_16x16x32_bf16(E[3][1], A1.v, d3, 0,0,0);
        const float r0 = __shfl(d0.x, c);
        float gf[16];
#pragma unroll
        for (int kk = 0; kk < 2; ++kk)
#pragma unroll
            for (int e = 0; e < 8; ++e)
                gf[8 * kk + e] = __expf(erow[(long long)t * KS + 32 * kk + 8 * h + e]);
        const int sh = 127 - (int)((__float_as_uint(r0) >> 23) & 0xff);
        const unsigned k16 = (unsigned)(unsigned short)(sh * 128);
        const unsigned kadd = (k16 << 16) | k16;
        const int mv = mrow[t];
        const f32x4 dd[4] = {d0, d1, d2, d3};
#pragma unroll
        for (int i = 0; i < 8; ++i) {
            const f32x4 dv = dd[i >> 1];
            const float x = (i & 1) ? dv.z : dv.x;
            const float y = (i & 1) ? dv.w : dv.y;
            const unsigned q = pkadd(cvtpk(x * gf[2 * i], y * gf[2 * i + 1]), kadd);
            aw[i] = mv ? q : aw[i];
        }
        M = mv ? (M - (float)sh * 0.693147180559945f) : M;
    }

    float val = 0.f;
#pragma unroll
    for (int kk = 0; kk < 2; ++kk)
#pragma unroll
        for (int wi = 0; wi < 4; ++wi) {
            const int j0 = 32 * kk + 8 * h + 2 * wi;
            const unsigned wq = aw[4 * kk + wi];
            val += bflo(wq) * __expf(endT[j0]);
            val += bfhi(wq) * __expf(endT[j0 + 1]);
        }
    val += __shfl_xor(val, 16);
    val += __shfl_xor(val, 32);
    if (l < 16) logZ[(long long)blockIdx.x * 16 + l] = M + __logf(val);
}

// ---------------------------------------------------------------------------
// Standalone gold (fallback path only).
// ---------------------------------------------------------------------------
__global__ __launch_bounds__(256) void crf_gold_kernel(
    const float* __restrict__ em, const int* __restrict__ tags,
    const int* __restrict__ mask, const float* __restrict__ trans,
    const float* __restrict__ startT, const float* __restrict__ endT,
    float* __restrict__ gold, int T)
{
    const int b = blockIdx.x;
    const int tid = threadIdx.x;
    const float* emb = em + (size_t)b * T * KS;
    const int* tb = tags + (size_t)b * T;
    const int* mb = mask + (size_t)b * T;

    float acc = 0.f;
    int cnt = 0;
    for (int t = tid; t < T; t += 256) {
        int tg = tb[t];
        int mv = mb[t];
        float mf = mv ? 1.f : 0.f;
        acc += emb[t * KS + tg] * mf;
        if (t >= 1) acc += trans[tb[t - 1] * KS + tg] * mf;
        cnt += mv ? 1 : 0;
    }
#pragma unroll
    for (int off = 32; off; off >>= 1) {
        acc += __shfl_xor(acc, off);
        cnt += __shfl_xor(cnt, off);
    }
    __shared__ float wacc[4];
    __shared__ int   wcnt[4];
    int wv = tid >> 6;
    if ((tid & 63) == 0) { wacc[wv] = acc; wcnt[wv] = cnt; }
    __syncthreads();
    if (tid == 0) {
        float a = wacc[0] + wacc[1] + wacc[2] + wacc[3];
        int   cc = wcnt[0] + wcnt[1] + wcnt[2] + wcnt[3];
        gold[b] = a + startT[tb[0]] + endT[tb[cc - 1]];
    }
}

// ---------------------------------------------------------------------------
// mean(logZ - gold) -> scalar
// ---------------------------------------------------------------------------
__global__ __launch_bounds__(512) void crf_reduce_kernel(
    const float* __restrict__ logZ, const float* __restrict__ gold,
    float* __restrict__ out, int B)
{
    int tid = threadIdx.x;
    float v = 0.f;
    for (int i = tid; i < B; i += 512) v += logZ[i] - gold[i];
#pragma unroll
    for (int off = 32; off; off >>= 1) v += __shfl_xor(v, off);
    __shared__ float ws[8];
    int w = tid >> 6;
    if ((tid & 63) == 0) ws[w] = v;
    __syncthreads();
    if (tid == 0) {
        float s = 0.f;
#pragma unroll
        for (int k = 0; k < 8; ++k) s += ws[k];
        out[0] = s / (float)B;
    }
}

// ---------------------------------------------------------------------------
extern "C" void kernel_launch(void* const* d_in, const int* in_sizes, int n_in,
                              void* d_out, int out_size, void* d_ws, size_t ws_size,
                              hipStream_t stream)
{
    const float* emissions = (const float*)d_in[0];
    const int*   tags      = (const int*)d_in[1];
    const int*   mask      = (const int*)d_in[2];
    const float* trans     = (const float*)d_in[3];
    const float* startT    = (const float*)d_in[4];
    const float* endT      = (const float*)d_in[5];

    const int T = TT;
    const int B = in_sizes[1] / T;

    float* logZ = (float*)d_ws;
    float* gold = logZ + B;

    const size_t g16 = (size_t)B * T * KS * 2;

    if (ws_size >= 8192 + g16 && (B % 32) == 0) {
        uint4* g = (uint4*)((char*)d_ws + 8192);
        const int nZ = B / 32;
        crf_expem_bf16<<<2048, 256, 0, stream>>>(
            emissions, g, (long long)B * T * KS / 8);
        crf_fused2<<<nZ + B, 256, 0, stream>>>(
            emissions, (const uint4*)g, mask, tags, trans, startT, endT,
            logZ, gold, nZ);
    } else {
        crf_logZ_fb<<<(B + 15) / 16, 64, 0, stream>>>(
            emissions, mask, trans, startT, endT, logZ);
        crf_gold_kernel<<<B, 256, 0, stream>>>(
            emissions, tags, mask, trans, startT, endT, gold, T);
    }
    crf_reduce_kernel<<<1, 512, 0, stream>>>(logZ, gold, (float*)d_out, B);
}

// Round 16
// 441.444 us; speedup vs baseline: 1.0023x; 1.0023x over previous
//
#include <hip/hip_runtime.h>
#include <hip/hip_bf16.h>

#define TT 1024
#define KS 64

typedef __attribute__((ext_vector_type(8))) short bf16x8;
typedef __attribute__((ext_vector_type(4))) float f32x4;

__device__ __forceinline__ unsigned short f2bf(float x) {
    union { __hip_bfloat16 h; unsigned short s; } u;
    u.h = __float2bfloat16(x);
    return u.s;
}
__device__ __forceinline__ float bflo(unsigned u) {
    union { unsigned v; float f; } w; w.v = u << 16; return w.f;
}
__device__ __forceinline__ float bfhi(unsigned u) {
    union { unsigned v; float f; } w; w.v = u & 0xFFFF0000u; return w.f;
}
__device__ __forceinline__ unsigned cvtpk(float a, float b) {
    unsigned r;
    asm("v_cvt_pk_bf16_f32 %0, %1, %2" : "=v"(r) : "v"(a), "v"(b));
    return r;
}
__device__ __forceinline__ unsigned pkadd(unsigned a, unsigned b) {
    unsigned r;
    asm("v_pk_add_u16 %0, %1, %2" : "=v"(r) : "v"(a), "v"(b));
    return r;
}

// ---------------------------------------------------------------------------
// Pre-pass: g = bf16 exp(emissions) (r11-proven), memory-bound streaming.
// ---------------------------------------------------------------------------
__global__ __launch_bounds__(256) void crf_expem_bf16(
    const float* __restrict__ em, uint4* __restrict__ g, long long n8)
{
    long long i = (long long)blockIdx.x * blockDim.x + threadIdx.x;
    const long long stride = (long long)gridDim.x * blockDim.x;
    const float4* p = (const float4*)em;
    for (; i < n8; i += stride) {
        float4 a = p[i * 2], b = p[i * 2 + 1];
        uint4 o;
        o.x = (unsigned)f2bf(__expf(a.x)) | ((unsigned)f2bf(__expf(a.y)) << 16);
        o.y = (unsigned)f2bf(__expf(a.z)) | ((unsigned)f2bf(__expf(a.w)) << 16);
        o.z = (unsigned)f2bf(__expf(b.x)) | ((unsigned)f2bf(__expf(b.y)) << 16);
        o.w = (unsigned)f2bf(__expf(b.z)) | ((unsigned)f2bf(__expf(b.w)) << 16);
        g[i] = o;
    }
}

// ---------------------------------------------------------------------------
// Fused kernel. Blocks [0,nZ): logZ, TWO interleaved 16-seq chains per wave
// (chain A = batches blk*32..+15, chain B = +16..+31). Chains are fully
// independent; issue order per t is [MFMA A][MFMA B][tail A][tail B] so each
// chain's dependency stalls hide under the other's work. E fragments are
// SHARED between chains (same transitions). Blocks [nZ,nZ+B): gold score.
//
// Verified pieces carried over unchanged: sigma lane-local repack
// (r7/r8/r11/r13), bf16-g unpack tail (r11), asm-volatile flat loads
// (anti-sink, r7) with straight-line control flow while in flight (r9),
// counted vmcnt + sched_barrier (rule #18), clamped refills + dummy masked
// step t=1024 (r8), deadbeat measure-once/apply-once controller (r10),
// M += sln2 exact bookkeeping.
// Ledger: 3 loads/slot, 2 slots/chain, 2 chains = 12 in flight; each
// sub-step waits vmcnt(9) (oldest slot's 3 done), consumes, reissues 3.
// ---------------------------------------------------------------------------
__global__ __launch_bounds__(256, 1) void crf_fused2(
    const float* __restrict__ em,
    const uint4* __restrict__ g4,       // bf16 exp(em)
    const int* __restrict__ mask,
    const int* __restrict__ tags,
    const float* __restrict__ trans,
    const float* __restrict__ startT,
    const float* __restrict__ endT,
    float* __restrict__ logZ,
    float* __restrict__ gold,
    int nZ)
{
    __shared__ float wacc[4];
    __shared__ int   wcnt[4];

    if ((int)blockIdx.x >= nZ) {
        // ---------------- gold path score (one block per batch) ------------
        const int b = (int)blockIdx.x - nZ;
        const int tid = threadIdx.x;
        const float* emb = em + (size_t)b * TT * KS;
        const int* tb = tags + (size_t)b * TT;
        const int* mb = mask + (size_t)b * TT;

        float acc = 0.f;
        int cnt = 0;
        for (int t = tid; t < TT; t += 256) {
            int tg = tb[t];
            int mv = mb[t];
            float mf = mv ? 1.f : 0.f;
            acc += emb[t * KS + tg] * mf;
            if (t >= 1) acc += trans[tb[t - 1] * KS + tg] * mf;
            cnt += mv ? 1 : 0;
        }
#pragma unroll
        for (int off = 32; off; off >>= 1) {
            acc += __shfl_xor(acc, off);
            cnt += __shfl_xor(cnt, off);
        }
        int wv = tid >> 6;
        if ((tid & 63) == 0) { wacc[wv] = acc; wcnt[wv] = cnt; }
        __syncthreads();
        if (tid == 0) {
            float a = wacc[0] + wacc[1] + wacc[2] + wacc[3];
            int   cc = wcnt[0] + wcnt[1] + wcnt[2] + wcnt[3];
            gold[b] = a + startT[tb[0]] + endT[tb[cc - 1]];
        }
        return;
    }

    // ---------------- logZ, two interleaved chains (wave 0 only) -----------
    if (threadIdx.x >= 64) return;
    __builtin_amdgcn_s_setprio(1);

    const int l = threadIdx.x;
    const int c = l & 15;
    const int h = l >> 4;
    const long long bA = (long long)blockIdx.x * 32 + c;
    const long long bB = bA + 16;

    // constant transition fragments (A-operand), shared by both chains
    const int sigc = 8 * (c >> 2) + (c & 3);
    bf16x8 E[4][2];
#pragma unroll
    for (int m = 0; m < 4; ++m) {
        const int col = 32 * (m >> 1) + 4 * (m & 1) + sigc;
#pragma unroll
        for (int kk = 0; kk < 2; ++kk) {
            union { unsigned short s[8]; bf16x8 v; } u;
#pragma unroll
            for (int e = 0; e < 8; ++e)
                u.s[e] = f2bf(__expf(trans[(32 * kk + 8 * h + e) * KS + col]));
            E[m][kk] = u.v;
        }
    }

    const long long embA = bA * (long long)TT * KS;
    const long long embB = bB * (long long)TT * KS;
    const unsigned long long gpA =
        (unsigned long long)(const void*)((const char*)g4 + embA * 2 + h * 16);
    const unsigned long long gpB =
        (unsigned long long)(const void*)((const char*)g4 + embB * 2 + h * 16);
    const unsigned long long mpA =
        (unsigned long long)(const void*)(mask + bA * TT);
    const unsigned long long mpB =
        (unsigned long long)(const void*)(mask + bB * TT);

    // ---- state init at t=0 for both chains ----
    unsigned awA0, awA1, awA2, awA3, awA4, awA5, awA6, awA7;
    unsigned awB0, awB1, awB2, awB3, awB4, awB5, awB6, awB7;
    {
        const float* erA = em + embA;
        const float* erB = em + embB;
        float wa[16], wb[16];
#pragma unroll
        for (int kk = 0; kk < 2; ++kk)
#pragma unroll
            for (int e = 0; e < 8; ++e) {
                const int j = 32 * kk + 8 * h + e;
                wa[8 * kk + e] = __expf(erA[j] + startT[j]);
                wb[8 * kk + e] = __expf(erB[j] + startT[j]);
            }
        awA0 = cvtpk(wa[0], wa[1]);   awA1 = cvtpk(wa[2], wa[3]);
        awA2 = cvtpk(wa[4], wa[5]);   awA3 = cvtpk(wa[6], wa[7]);
        awA4 = cvtpk(wa[8], wa[9]);   awA5 = cvtpk(wa[10], wa[11]);
        awA6 = cvtpk(wa[12], wa[13]); awA7 = cvtpk(wa[14], wa[15]);
        awB0 = cvtpk(wb[0], wb[1]);   awB1 = cvtpk(wb[2], wb[3]);
        awB2 = cvtpk(wb[4], wb[5]);   awB3 = cvtpk(wb[6], wb[7]);
        awB4 = cvtpk(wb[8], wb[9]);   awB5 = cvtpk(wb[10], wb[11]);
        awB6 = cvtpk(wb[12], wb[13]); awB7 = cvtpk(wb[14], wb[15]);
    }
    float MA = 0.f, MB = 0.f;

    // ---- prefetch slots: depth 2 per chain, 3 loads per slot ----
    uint4 gaA[2], gcA[2], gaB[2], gcB[2];
    int   mvA[2], mvB[2];
#pragma unroll
    for (int u = 0; u < 2; ++u) {
        const unsigned long long aa = gpA + (unsigned long long)(1 + u) * 128ull;
        const unsigned long long ab = gpB + (unsigned long long)(1 + u) * 128ull;
        const unsigned long long ma = mpA + (unsigned long long)(1 + u) * 4ull;
        const unsigned long long mb = mpB + (unsigned long long)(1 + u) * 4ull;
        asm volatile("global_load_dwordx4 %0, %1, off" : "=&v"(gaA[u]) : "v"(aa));
        asm volatile("global_load_dwordx4 %0, %1, off offset:64" : "=&v"(gcA[u]) : "v"(aa));
        asm volatile("global_load_dword %0, %1, off" : "=&v"(mvA[u]) : "v"(ma));
        asm volatile("global_load_dwordx4 %0, %1, off" : "=&v"(gaB[u]) : "v"(ab));
        asm volatile("global_load_dwordx4 %0, %1, off offset:64" : "=&v"(gcB[u]) : "v"(ab));
        asm volatile("global_load_dword %0, %1, off" : "=&v"(mvB[u]) : "v"(mb));
    }

    unsigned kaddA = 0, kaddB = 0;
    float sln2A = 0.f, sln2B = 0.f;

#define CRF_CTRL(W0, W4, KADD, SLN2) do {                                      \
    const unsigned l0 = (W0) & 0xffffu, h0 = (W0) >> 16;                       \
    const unsigned l4 = (W4) & 0xffffu, h4 = (W4) >> 16;                       \
    unsigned um = l0 > h0 ? l0 : h0;                                           \
    um = um > l4 ? um : l4;  um = um > h4 ? um : h4;                           \
    unsigned sx = (unsigned)__shfl_xor((int)um, 16); um = um > sx ? um : sx;   \
    sx = (unsigned)__shfl_xor((int)um, 32);          um = um > sx ? um : sx;   \
    const unsigned k16 = (0x3F80u - (um & 0x7F80u)) & 0xffffu;                 \
    KADD = (k16 << 16) | k16;                                                  \
    SLN2 = (float)((int)((um >> 7) & 0xffu) - 127) * 0.693147180559945f;       \
} while (0)

// one chain's tail+refill (used inside the double-step)
#define CRF_TAIL(SFX, t, u, APPLY, DOCTRL, GP, MP, d0, d1, d2, d3)             \
do {                                                                           \
    const uint4 v0 = ga##SFX[u], v1 = gc##SFX[u];                              \
    const int mvv = ((t) <= TT - 1) ? mv##SFX[u] : 0;                          \
    {                                                                          \
        const int tn = ((t) + 2 <= TT - 1) ? ((t) + 2) : (TT - 1);             \
        const unsigned long long a  = (GP) + (unsigned long long)tn * 128ull;  \
        const unsigned long long ma = (MP) + (unsigned long long)tn * 4ull;    \
        asm volatile("global_load_dwordx4 %0, %1, off" : "=&v"(ga##SFX[u]) : "v"(a)); \
        asm volatile("global_load_dwordx4 %0, %1, off offset:64" : "=&v"(gc##SFX[u]) : "v"(a)); \
        asm volatile("global_load_dword %0, %1, off" : "=&v"(mv##SFX[u]) : "v"(ma)); \
    }                                                                          \
    const float g00 = bflo(v0.x), g01 = bfhi(v0.x);                            \
    const float g02 = bflo(v0.y), g03 = bfhi(v0.y);                            \
    const float g10 = bflo(v0.z), g11 = bfhi(v0.z);                            \
    const float g12 = bflo(v0.w), g13 = bfhi(v0.w);                            \
    const float g20 = bflo(v1.x), g21 = bfhi(v1.x);                            \
    const float g22 = bflo(v1.y), g23 = bfhi(v1.y);                            \
    const float g30 = bflo(v1.z), g31 = bfhi(v1.z);                            \
    const float g32 = bflo(v1.w), g33 = bfhi(v1.w);                            \
    unsigned q0, q1, q2, q3, q4, q5, q6, q7;                                   \
    if (APPLY) {                                                               \
        q0 = pkadd(cvtpk(d0.x * g00, d0.y * g01), kadd##SFX);                  \
        q1 = pkadd(cvtpk(d0.z * g02, d0.w * g03), kadd##SFX);                  \
        q2 = pkadd(cvtpk(d1.x * g10, d1.y * g11), kadd##SFX);                  \
        q3 = pkadd(cvtpk(d1.z * g12, d1.w * g13), kadd##SFX);                  \
        q4 = pkadd(cvtpk(d2.x * g20, d2.y * g21), kadd##SFX);                  \
        q5 = pkadd(cvtpk(d2.z * g22, d2.w * g23), kadd##SFX);                  \
        q6 = pkadd(cvtpk(d3.x * g30, d3.y * g31), kadd##SFX);                  \
        q7 = pkadd(cvtpk(d3.z * g32, d3.w * g33), kadd##SFX);                  \
    } else {                                                                   \
        q0 = cvtpk(d0.x * g00, d0.y * g01);                                    \
        q1 = cvtpk(d0.z * g02, d0.w * g03);                                    \
        q2 = cvtpk(d1.x * g10, d1.y * g11);                                    \
        q3 = cvtpk(d1.z * g12, d1.w * g13);                                    \
        q4 = cvtpk(d2.x * g20, d2.y * g21);                                    \
        q5 = cvtpk(d2.z * g22, d2.w * g23);                                    \
        q6 = cvtpk(d3.x * g30, d3.y * g31);                                    \
        q7 = cvtpk(d3.z * g32, d3.w * g33);                                    \
    }                                                                          \
    aw##SFX##0 = mvv ? q0 : aw##SFX##0; aw##SFX##1 = mvv ? q1 : aw##SFX##1;    \
    aw##SFX##2 = mvv ? q2 : aw##SFX##2; aw##SFX##3 = mvv ? q3 : aw##SFX##3;    \
    aw##SFX##4 = mvv ? q4 : aw##SFX##4; aw##SFX##5 = mvv ? q5 : aw##SFX##5;    \
    aw##SFX##6 = mvv ? q6 : aw##SFX##6; aw##SFX##7 = mvv ? q7 : aw##SFX##7;    \
    if (APPLY) { M##SFX = mvv ? (M##SFX + sln2##SFX) : M##SFX; }               \
    if (DOCTRL) CRF_CTRL(aw##SFX##0, aw##SFX##4, kadd##SFX, sln2##SFX);        \
} while (0)

#define CRF_DSTEP(t, u, APPLY, DOCTRL) do {                                    \
    union { unsigned uu[4]; bf16x8 v; } Aa0, Aa1, Ba0, Ba1;                    \
    Aa0.uu[0] = awA0; Aa0.uu[1] = awA1; Aa0.uu[2] = awA2; Aa0.uu[3] = awA3;    \
    Aa1.uu[0] = awA4; Aa1.uu[1] = awA5; Aa1.uu[2] = awA6; Aa1.uu[3] = awA7;    \
    Ba0.uu[0] = awB0; Ba0.uu[1] = awB1; Ba0.uu[2] = awB2; Ba0.uu[3] = awB3;    \
    Ba1.uu[0] = awB4; Ba1.uu[1] = awB5; Ba1.uu[2] = awB6; Ba1.uu[3] = awB7;    \
    const f32x4 z = {0.f, 0.f, 0.f, 0.f};                                      \
    f32x4 dA0 = __builtin_amdgcn_mfma_f32_16x16x32_bf16(E[0][0], Aa0.v, z,0,0,0); \
    f32x4 dA1 = __builtin_amdgcn_mfma_f32_16x16x32_bf16(E[1][0], Aa0.v, z,0,0,0); \
    f32x4 dA2 = __builtin_amdgcn_mfma_f32_16x16x32_bf16(E[2][0], Aa0.v, z,0,0,0); \
    f32x4 dA3 = __builtin_amdgcn_mfma_f32_16x16x32_bf16(E[3][0], Aa0.v, z,0,0,0); \
    dA0 = __builtin_amdgcn_mfma_f32_16x16x32_bf16(E[0][1], Aa1.v, dA0, 0,0,0); \
    dA1 = __builtin_amdgcn_mfma_f32_16x16x32_bf16(E[1][1], Aa1.v, dA1, 0,0,0); \
    dA2 = __builtin_amdgcn_mfma_f32_16x16x32_bf16(E[2][1], Aa1.v, dA2, 0,0,0); \
    dA3 = __builtin_amdgcn_mfma_f32_16x16x32_bf16(E[3][1], Aa1.v, dA3, 0,0,0); \
    f32x4 dB0 = __builtin_amdgcn_mfma_f32_16x16x32_bf16(E[0][0], Ba0.v, z,0,0,0); \
    f32x4 dB1 = __builtin_amdgcn_mfma_f32_16x16x32_bf16(E[1][0], Ba0.v, z,0,0,0); \
    f32x4 dB2 = __builtin_amdgcn_mfma_f32_16x16x32_bf16(E[2][0], Ba0.v, z,0,0,0); \
    f32x4 dB3 = __builtin_amdgcn_mfma_f32_16x16x32_bf16(E[3][0], Ba0.v, z,0,0,0); \
    dB0 = __builtin_amdgcn_mfma_f32_16x16x32_bf16(E[0][1], Ba1.v, dB0, 0,0,0); \
    dB1 = __builtin_amdgcn_mfma_f32_16x16x32_bf16(E[1][1], Ba1.v, dB1, 0,0,0); \
    dB2 = __builtin_amdgcn_mfma_f32_16x16x32_bf16(E[2][1], Ba1.v, dB2, 0,0,0); \
    dB3 = __builtin_amdgcn_mfma_f32_16x16x32_bf16(E[3][1], Ba1.v, dB3, 0,0,0); \
    asm volatile("s_waitcnt vmcnt(9)" ::: "memory");                           \
    __builtin_amdgcn_sched_barrier(0);                                         \
    CRF_TAIL(A, t, u, APPLY, DOCTRL, gpA, mpA, dA0, dA1, dA2, dA3);            \
    asm volatile("s_waitcnt vmcnt(9)" ::: "memory");                           \
    __builtin_amdgcn_sched_barrier(0);                                         \
    CRF_TAIL(B, t, u, APPLY, DOCTRL, gpB, mpB, dB0, dB1, dB2, dB3);            \
} while (0)

    // groups of 4 t-steps; slots u = 0,1,0,1; measure @ds0, apply once @ds2
    for (int t0 = 1; t0 < TT + 1; t0 += 4) {
        CRF_DSTEP(t0 + 0, 0, 0, 1);
        CRF_DSTEP(t0 + 1, 1, 0, 0);
        CRF_DSTEP(t0 + 2, 0, 1, 0);
        CRF_DSTEP(t0 + 3, 1, 0, 0);
    }
#undef CRF_DSTEP
#undef CRF_TAIL
#undef CRF_CTRL
    __builtin_amdgcn_s_setprio(0);

    // logZ = M + log(sum_j w_j * exp(end_j)) for both chains
    float endE[16];
#pragma unroll
    for (int kk = 0; kk < 2; ++kk)
#pragma unroll
        for (int wi = 0; wi < 4; ++wi) {
            const int j0 = 32 * kk + 8 * h + 2 * wi;
            endE[8 * kk + 2 * wi] = __expf(endT[j0]);
            endE[8 * kk + 2 * wi + 1] = __expf(endT[j0 + 1]);
        }
    float valA = 0.f, valB = 0.f;
    {
        const unsigned aA[8] = {awA0, awA1, awA2, awA3, awA4, awA5, awA6, awA7};
        const unsigned aB[8] = {awB0, awB1, awB2, awB3, awB4, awB5, awB6, awB7};
#pragma unroll
        for (int kk = 0; kk < 2; ++kk)
#pragma unroll
            for (int wi = 0; wi < 4; ++wi) {
                const unsigned wqA = aA[4 * kk + wi];
                const unsigned wqB = aB[4 * kk + wi];
                valA += bflo(wqA) * endE[8 * kk + 2 * wi];
                valA += bfhi(wqA) * endE[8 * kk + 2 * wi + 1];
                valB += bflo(wqB) * endE[8 * kk + 2 * wi];
                valB += bfhi(wqB) * endE[8 * kk + 2 * wi + 1];
            }
    }
    valA += __shfl_xor(valA, 16);
    valA += __shfl_xor(valA, 32);
    valB += __shfl_xor(valB, 16);
    valB += __shfl_xor(valB, 32);
    if (l < 16) {
        logZ[(long long)blockIdx.x * 32 + l]      = MA + __logf(valA);
        logZ[(long long)blockIdx.x * 32 + 16 + l] = MB + __logf(valB);
    }
}

// ---------------------------------------------------------------------------
// Fallback (workspace too small): r7-verified kernel, exp on the fly.
// ---------------------------------------------------------------------------
__global__ __launch_bounds__(64, 1) void crf_logZ_fb(
    const float* __restrict__ em, const int* __restrict__ mask,
    const float* __restrict__ trans, const float* __restrict__ startT,
    const float* __restrict__ endT, float* __restrict__ logZ)
{
    const int l = threadIdx.x;
    const int c = l & 15;
    const int h = l >> 4;
    const long long b = (long long)blockIdx.x * 16 + c;

    const int sigc = 8 * (c >> 2) + (c & 3);
    bf16x8 E[4][2];
#pragma unroll
    for (int m = 0; m < 4; ++m) {
        const int col = 32 * (m >> 1) + 4 * (m & 1) + sigc;
#pragma unroll
        for (int kk = 0; kk < 2; ++kk) {
            union { unsigned short s[8]; bf16x8 v; } u;
#pragma unroll
            for (int e = 0; e < 8; ++e)
                u.s[e] = f2bf(__expf(trans[(32 * kk + 8 * h + e) * KS + col]));
            E[m][kk] = u.v;
        }
    }
    const long long embase = b * (long long)TT * KS;
    const int* mrow = mask + b * TT;
    const float* erow = em + embase;

    unsigned aw[8];
    {
        float w0[16];
#pragma unroll
        for (int kk = 0; kk < 2; ++kk)
#pragma unroll
            for (int e = 0; e < 8; ++e) {
                const int j = 32 * kk + 8 * h + e;
                w0[8 * kk + e] = __expf(erow[j] + startT[j]);
            }
#pragma unroll
        for (int i = 0; i < 8; ++i) aw[i] = cvtpk(w0[2 * i], w0[2 * i + 1]);
    }
    float M = 0.f;

    for (int t = 1; t < TT; ++t) {
        union { unsigned uu[4]; bf16x8 v; } A0, A1;
#pragma unroll
        for (int i = 0; i < 4; ++i) { A0.uu[i] = aw[i]; A1.uu[i] = aw[4 + i]; }
        const f32x4 z = {0.f, 0.f, 0.f, 0.f};
        f32x4 d0 = __builtin_amdgcn_mfma_f32_16x16x32_bf16(E[0][0], A0.v, z,0,0,0);
        f32x4 d1 = __builtin_amdgcn_mfma_f32_16x16x32_bf16(E[1][0], A0.v, z,0,0,0);
        f32x4 d2 = __builtin_amdgcn_mfma_f32_16x16x32_bf16(E[2][0], A0.v, z,0,0,0);
        f32x4 d3 = __builtin_amdgcn_mfma_f32_16x16x32_bf16(E[3][0], A0.v, z,0,0,0);
        d0 = __builtin_amdgcn_mfma_f32_16x16x32_bf16(E[0][1], A1.v, d0, 0,0,0);
        d1 = __builtin_amdgcn_mfma_f32_16x16x32_bf16(E[1][1], A1.v, d1, 0,0,0);
        d2 = __builtin_amdgcn_mfma_f32_16x16x32_bf16(E[2][1], A1.v, d2, 0,0,0);
        d3 = __builtin_amdgcn_mfma_f32_16x16x32_bf16(E[3][1], A1.v, d3, 0,0,0);
        const float r0 = __shfl(d0.x, c);
        float gf[16];
#pragma unroll
        for (int kk = 0; kk < 2; ++kk)
#pragma unroll
            for (int e = 0; e < 8; ++e)
                gf[8 * kk + e] = __expf(erow[(long long)t * KS + 32 * kk + 8 * h + e]);
        const int sh = 127 - (int)((__float_as_uint(r0) >> 23) & 0xff);
        const unsigned k16 = (unsigned)(unsigned short)(sh * 128);
        const unsigned kadd = (k16 << 16) | k16;
        const int mv = mrow[t];
        const f32x4 dd[4] = {d0, d1, d2, d3};
#pragma unroll
        for (int i = 0; i < 8; ++i) {
            const f32x4 dv = dd[i >> 1];
            const float x = (i & 1) ? dv.z : dv.x;
            const float y = (i & 1) ? dv.w : dv.y;
            const unsigned q = pkadd(cvtpk(x * gf[2 * i], y * gf[2 * i + 1]), kadd);
            aw[i] = mv ? q : aw[i];
        }
        M = mv ? (M - (float)sh * 0.693147180559945f) : M;
    }

    float val = 0.f;
#pragma unroll
    for (int kk = 0; kk < 2; ++kk)
#pragma unroll
        for (int wi = 0; wi < 4; ++wi) {
            const int j0 = 32 * kk + 8 * h + 2 * wi;
            const unsigned wq = aw[4 * kk + wi];
            val += bflo(wq) * __expf(endT[j0]);
            val += bfhi(wq) * __expf(endT[j0 + 1]);
        }
    val += __shfl_xor(val, 16);
    val += __shfl_xor(val, 32);
    if (l < 16) logZ[(long long)blockIdx.x * 16 + l] = M + __logf(val);
}

// ---------------------------------------------------------------------------
// Standalone gold (fallback path only).
// ---------------------------------------------------------------------------
__global__ __launch_bounds__(256) void crf_gold_kernel(
    const float* __restrict__ em, const int* __restrict__ tags,
    const int* __restrict__ mask, const float* __restrict__ trans,
    const float* __restrict__ startT, const float* __restrict__ endT,
    float* __restrict__ gold, int T)
{
    const int b = blockIdx.x;
    const int tid = threadIdx.x;
    const float* emb = em + (size_t)b * T * KS;
    const int* tb = tags + (size_t)b * T;
    const int* mb = mask + (size_t)b * T;

    float acc = 0.f;
    int cnt = 0;
    for (int t = tid; t < T; t += 256) {
        int tg = tb[t];
        int mv = mb[t];
        float mf = mv ? 1.f : 0.f;
        acc += emb[t * KS + tg] * mf;
        if (t >= 1) acc += trans[tb[t - 1] * KS + tg] * mf;
        cnt += mv ? 1 : 0;
    }
#pragma unroll
    for (int off = 32; off; off >>= 1) {
        acc += __shfl_xor(acc, off);
        cnt += __shfl_xor(cnt, off);
    }
    __shared__ float wacc[4];
    __shared__ int   wcnt[4];
    int wv = tid >> 6;
    if ((tid & 63) == 0) { wacc[wv] = acc; wcnt[wv] = cnt; }
    __syncthreads();
    if (tid == 0) {
        float a = wacc[0] + wacc[1] + wacc[2] + wacc[3];
        int   cc = wcnt[0] + wcnt[1] + wcnt[2] + wcnt[3];
        gold[b] = a + startT[tb[0]] + endT[tb[cc - 1]];
    }
}

// ---------------------------------------------------------------------------
// mean(logZ - gold) -> scalar
// ---------------------------------------------------------------------------
__global__ __launch_bounds__(512) void crf_reduce_kernel(
    const float* __restrict__ logZ, const float* __restrict__ gold,
    float* __restrict__ out, int B)
{
    int tid = threadIdx.x;
    float v = 0.f;
    for (int i = tid; i < B; i += 512) v += logZ[i] - gold[i];
#pragma unroll
    for (int off = 32; off; off >>= 1) v += __shfl_xor(v, off);
    __shared__ float ws[8];
    int w = tid >> 6;
    if ((tid & 63) == 0) ws[w] = v;
    __syncthreads();
    if (tid == 0) {
        float s = 0.f;
#pragma unroll
        for (int k = 0; k < 8; ++k) s += ws[k];
        out[0] = s / (float)B;
    }
}

// ---------------------------------------------------------------------------
extern "C" void kernel_launch(void* const* d_in, const int* in_sizes, int n_in,
                              void* d_out, int out_size, void* d_ws, size_t ws_size,
                              hipStream_t stream)
{
    const float* emissions = (const float*)d_in[0];
    const int*   tags      = (const int*)d_in[1];
    const int*   mask      = (const int*)d_in[2];
    const float* trans     = (const float*)d_in[3];
    const float* startT    = (const float*)d_in[4];
    const float* endT      = (const float*)d_in[5];

    const int T = TT;
    const int B = in_sizes[1] / T;

    float* logZ = (float*)d_ws;
    float* gold = logZ + B;

    const size_t g16 = (size_t)B * T * KS * 2;

    if (ws_size >= 8192 + g16 && (B % 32) == 0) {
        uint4* g = (uint4*)((char*)d_ws + 8192);
        const int nZ = B / 32;
        crf_expem_bf16<<<2048, 256, 0, stream>>>(
            emissions, g, (long long)B * T * KS / 8);
        crf_fused2<<<nZ + B, 256, 0, stream>>>(
            emissions, (const uint4*)g, mask, tags, trans, startT, endT,
            logZ, gold, nZ);
    } else {
        crf_logZ_fb<<<(B + 15) / 16, 64, 0, stream>>>(
            emissions, mask, trans, startT, endT, logZ);
        crf_gold_kernel<<<B, 256, 0, stream>>>(
            emissions, tags, mask, trans, startT, endT, gold, T);
    }
    crf_reduce_kernel<<<1, 512, 0, stream>>>(logZ, gold, (float*)d_out, B);
}